// Round 7
// baseline (400.747 us; speedup 1.0000x reference)
//
#include <hip/hip_runtime.h>

typedef _Float16 half_t;
typedef _Float16 f16x8 __attribute__((ext_vector_type(8)));
typedef _Float16 f16x4 __attribute__((ext_vector_type(4)));
typedef _Float16 f16x2 __attribute__((ext_vector_type(2)));
typedef float fx4 __attribute__((ext_vector_type(4)));

typedef __attribute__((address_space(1))) const unsigned int as1_cuint;
typedef __attribute__((address_space(3))) unsigned int as3_uint;

__device__ __forceinline__ void gld16(const void* g, void* l) {
    __builtin_amdgcn_global_load_lds((as1_cuint*)g, (as3_uint*)l, 16, 0, 0);
}

// ---------------------------------------------------------------------------
// GEMM: C[m][n] = sum_k A[m][k] * B[n][k]   (B row-major [N][K], i.e. B^T input)
// 128x128 tile, K-step 32, 4 waves each computing a 64x64 quadrant (4x4 frags).
// Grid: blockIdx.x = M-tile, blockIdx.y = N-tile (XCD swizzle: blocks sharing
// an A-tile land on the same XCD => A re-reads are same-XCD L2 hits).
// MODE 1: QK epilogue: z=0 -> Q, z=1 -> K, layout [b,h,s,dk]  (coalesced)
// MODE 4: split-K over blockIdx.z; store fp16 PARTIAL to oZ[m*N+n].
//         With gridDim.z==1 this is a plain fp16 GEMM store (used for V^T:
//         A=wv, B=h => out[dk_g][b*2048+s], fully coalesced — the old
//         scatter-store V^T epilogue cost ~100us of 2B/4KB-stride writes).
// ---------------------------------------------------------------------------
template<int MODE>
__global__ __launch_bounds__(256, 2)
void gemm_bt(const half_t* __restrict__ A,
             const half_t* __restrict__ B0, const half_t* __restrict__ B1,
             const half_t* __restrict__ B2,
             half_t* o0, half_t* o1, half_t* o2, half_t* o3,
             int M, int N, int K)
{
    __shared__ half_t sA[128 * 32];
    __shared__ half_t sB[128 * 32];
    const int tid = threadIdx.x;
    const int wid = tid >> 6, lane = tid & 63;
    const int lm = lane & 15, lg = lane >> 4;
    const int wr = wid >> 1, wc = wid & 1;
    const int m0 = blockIdx.x * 128, n0 = blockIdx.y * 128;

    const half_t* Bp = B0;
    half_t* outb = o0;
    if (MODE == 1) {
        if (blockIdx.z == 1) { Bp = B1; outb = o1; }
    }
    if (MODE == 4) {
        if (blockIdx.z == 1) outb = o1;
        else if (blockIdx.z == 2) outb = o2;
        else if (blockIdx.z == 3) outb = o3;
    }

    int Keff = K, koff = 0;
    if (MODE == 4) { Keff = K / gridDim.z; koff = blockIdx.z * Keff; }

    const int srow = tid >> 2;
    const int scolb = (tid & 3) << 4;
    const char* gA = (const char*)(A + (size_t)(m0 + srow) * K + koff) + scolb;
    const char* gB = (const char*)(Bp + (size_t)(n0 + srow) * K + koff) + scolb;
    const size_t rstep = (size_t)64 * K * sizeof(half_t);
    char* lA = (char*)sA + tid * 16;
    char* lB = (char*)sB + tid * 16;

    fx4 acc[4][4] = {};

    for (int kt = 0; kt < Keff; kt += 32) {
        gld16(gA, lA);
        gld16(gA + rstep, lA + 4096);
        gld16(gB, lB);
        gld16(gB + rstep, lB + 4096);
        gA += 64; gB += 64;
        __syncthreads();
        f16x8 aF[4], bF[4];
#pragma unroll
        for (int mi = 0; mi < 4; mi++)
            aF[mi] = *(const f16x8*)(sA + (wr * 64 + mi * 16 + lm) * 32 + lg * 8);
#pragma unroll
        for (int ni = 0; ni < 4; ni++)
            bF[ni] = *(const f16x8*)(sB + (wc * 64 + ni * 16 + lm) * 32 + lg * 8);
#pragma unroll
        for (int mi = 0; mi < 4; mi++)
#pragma unroll
            for (int ni = 0; ni < 4; ni++)
                acc[mi][ni] = __builtin_amdgcn_mfma_f32_16x16x32_f16(aF[mi], bF[ni], acc[mi][ni], 0, 0, 0);
        __syncthreads();
    }

#pragma unroll
    for (int mi = 0; mi < 4; mi++) {
#pragma unroll
        for (int ni = 0; ni < 4; ni++) {
#pragma unroll
            for (int r = 0; r < 4; r++) {
                int m = m0 + wr * 64 + mi * 16 + lg * 4 + r;
                int n = n0 + wc * 64 + ni * 16 + lm;
                float v = acc[mi][ni][r];
                size_t idx = (size_t)m * N + n;
                if (MODE == 1) {
                    int b = m >> 11, s = m & 2047, hh = n >> 6, dk = n & 63;
                    outb[((size_t)(b * 16 + hh) * 2048 + s) * 64 + dk] = (half_t)v;
                } else {
                    outb[idx] = (half_t)v;     // plain / partial, coalesced
                }
            }
        }
    }
}

// ---------------------------------------------------------------------------
// Fused SwiGLU up+gate GEMM: u = A·B1^T, g = A·B2^T (A staged once,
// 32 MFMA per K-step); out = silu(u)*g as fp16.
// ---------------------------------------------------------------------------
__global__ __launch_bounds__(256, 2)
void gemm_dual(const half_t* __restrict__ A,
               const half_t* __restrict__ B1, const half_t* __restrict__ B2,
               half_t* __restrict__ out, int M, int N, int K)
{
    __shared__ half_t sA[128 * 32];
    __shared__ half_t sB1[128 * 32];
    __shared__ half_t sB2[128 * 32];
    const int tid = threadIdx.x;
    const int wid = tid >> 6, lane = tid & 63;
    const int lm = lane & 15, lg = lane >> 4;
    const int wr = wid >> 1, wc = wid & 1;
    const int m0 = blockIdx.x * 128, n0 = blockIdx.y * 128;

    const int srow = tid >> 2;
    const int scolb = (tid & 3) << 4;
    const char* gA = (const char*)(A + (size_t)(m0 + srow) * K) + scolb;
    const char* gB1 = (const char*)(B1 + (size_t)(n0 + srow) * K) + scolb;
    const char* gB2 = (const char*)(B2 + (size_t)(n0 + srow) * K) + scolb;
    const size_t rstep = (size_t)64 * K * sizeof(half_t);
    char* lA = (char*)sA + tid * 16;
    char* lB1 = (char*)sB1 + tid * 16;
    char* lB2 = (char*)sB2 + tid * 16;

    fx4 accU[4][4] = {};
    fx4 accG[4][4] = {};

    for (int kt = 0; kt < K; kt += 32) {
        gld16(gA, lA);
        gld16(gA + rstep, lA + 4096);
        gld16(gB1, lB1);
        gld16(gB1 + rstep, lB1 + 4096);
        gld16(gB2, lB2);
        gld16(gB2 + rstep, lB2 + 4096);
        gA += 64; gB1 += 64; gB2 += 64;
        __syncthreads();
        f16x8 aF[4], b1F[4], b2F[4];
#pragma unroll
        for (int mi = 0; mi < 4; mi++)
            aF[mi] = *(const f16x8*)(sA + (wr * 64 + mi * 16 + lm) * 32 + lg * 8);
#pragma unroll
        for (int ni = 0; ni < 4; ni++) {
            b1F[ni] = *(const f16x8*)(sB1 + (wc * 64 + ni * 16 + lm) * 32 + lg * 8);
            b2F[ni] = *(const f16x8*)(sB2 + (wc * 64 + ni * 16 + lm) * 32 + lg * 8);
        }
#pragma unroll
        for (int mi = 0; mi < 4; mi++)
#pragma unroll
            for (int ni = 0; ni < 4; ni++) {
                accU[mi][ni] = __builtin_amdgcn_mfma_f32_16x16x32_f16(aF[mi], b1F[ni], accU[mi][ni], 0, 0, 0);
                accG[mi][ni] = __builtin_amdgcn_mfma_f32_16x16x32_f16(aF[mi], b2F[ni], accG[mi][ni], 0, 0, 0);
            }
        __syncthreads();
    }

#pragma unroll
    for (int mi = 0; mi < 4; mi++) {
#pragma unroll
        for (int ni = 0; ni < 4; ni++) {
#pragma unroll
            for (int r = 0; r < 4; r++) {
                int m = m0 + wr * 64 + mi * 16 + lg * 4 + r;
                int n = n0 + wc * 64 + ni * 16 + lm;
                float u = accU[mi][ni][r];
                float g = accG[mi][ni][r];
                out[(size_t)m * N + n] = (half_t)(u / (1.f + __expf(-u)) * g);
            }
        }
    }
}

// ---------------------------------------------------------------------------
// Fused O-proj combine + residual + RMSNorm:
//   t = x + p0 + p1;  outF = t;  outH = rmsnorm(t)*w  (fp16)
// ---------------------------------------------------------------------------
__global__ __launch_bounds__(256, 4)
void addnorm_k(const float* __restrict__ x,
               const half_t* __restrict__ p0, const half_t* __restrict__ p1,
               const float* __restrict__ w,
               float* __restrict__ outF, half_t* __restrict__ outH)
{
    int row = blockIdx.x * 4 + (threadIdx.x >> 6);
    int lane = threadIdx.x & 63;
    const float4* xr = (const float4*)(x + (size_t)row * 1024);
    const f16x4* p0r = (const f16x4*)(p0 + (size_t)row * 1024);
    const f16x4* p1r = (const f16x4*)(p1 + (size_t)row * 1024);
    float4 v[4];
    float s = 0.f;
#pragma unroll
    for (int i = 0; i < 4; i++) {
        float4 xv = xr[lane + 64 * i];
        f16x4 a0 = p0r[lane + 64 * i];
        f16x4 a1 = p1r[lane + 64 * i];
        v[i].x = xv.x + (float)a0[0] + (float)a1[0];
        v[i].y = xv.y + (float)a0[1] + (float)a1[1];
        v[i].z = xv.z + (float)a0[2] + (float)a1[2];
        v[i].w = xv.w + (float)a0[3] + (float)a1[3];
        s += v[i].x * v[i].x + v[i].y * v[i].y + v[i].z * v[i].z + v[i].w * v[i].w;
    }
#pragma unroll
    for (int o = 32; o > 0; o >>= 1) s += __shfl_xor(s, o);
    float inv = rsqrtf(s * (1.f / 1024.f) + 1e-5f);
    const float4* w4 = (const float4*)w;
    float4* oF = (float4*)(outF + (size_t)row * 1024);
    f16x4* oH = (f16x4*)(outH + (size_t)row * 1024);
#pragma unroll
    for (int i = 0; i < 4; i++) {
        oF[lane + 64 * i] = v[i];
        float4 wv = w4[lane + 64 * i];
        f16x4 ov = { (half_t)(v[i].x * inv * wv.x), (half_t)(v[i].y * inv * wv.y),
                     (half_t)(v[i].z * inv * wv.z), (half_t)(v[i].w * inv * wv.w) };
        oH[lane + 64 * i] = ov;
    }
}

// ---------------------------------------------------------------------------
// Split-K=4 combine: out = out + p0 + p1 + p2 + p3
// ---------------------------------------------------------------------------
__global__ __launch_bounds__(256, 8)
void reduce4_k(const half_t* __restrict__ p0, const half_t* __restrict__ p1,
               const half_t* __restrict__ p2, const half_t* __restrict__ p3,
               float* __restrict__ out, int n4)
{
    int i = blockIdx.x * 256 + threadIdx.x;
    if (i >= n4) return;
    float4 b = ((const float4*)out)[i];
    f16x4 a0 = ((const f16x4*)p0)[i];
    f16x4 a1 = ((const f16x4*)p1)[i];
    f16x4 a2 = ((const f16x4*)p2)[i];
    f16x4 a3 = ((const f16x4*)p3)[i];
    float4 o = { b.x + (float)a0[0] + (float)a1[0] + (float)a2[0] + (float)a3[0],
                 b.y + (float)a0[1] + (float)a1[1] + (float)a2[1] + (float)a3[1],
                 b.z + (float)a0[2] + (float)a1[2] + (float)a2[2] + (float)a3[2],
                 b.w + (float)a0[3] + (float)a1[3] + (float)a2[3] + (float)a3[3] };
    ((float4*)out)[i] = o;
}

// ---------------------------------------------------------------------------
// RMSNorm: one wave per row of 1024 fp32, output fp16
// ---------------------------------------------------------------------------
__global__ __launch_bounds__(256, 4)
void rmsnorm_k(const float* __restrict__ x, const float* __restrict__ w,
               half_t* __restrict__ out)
{
    int row = blockIdx.x * 4 + (threadIdx.x >> 6);
    int lane = threadIdx.x & 63;
    const float4* xr = (const float4*)(x + (size_t)row * 1024);
    float4 v[4];
    float s = 0.f;
#pragma unroll
    for (int i = 0; i < 4; i++) {
        v[i] = xr[lane + 64 * i];
        s += v[i].x * v[i].x + v[i].y * v[i].y + v[i].z * v[i].z + v[i].w * v[i].w;
    }
#pragma unroll
    for (int o = 32; o > 0; o >>= 1) s += __shfl_xor(s, o);
    float inv = rsqrtf(s * (1.f / 1024.f) + 1e-5f);
    const float4* w4 = (const float4*)w;
    f16x4* o4 = (f16x4*)(out + (size_t)row * 1024);
#pragma unroll
    for (int i = 0; i < 4; i++) {
        float4 wv = w4[lane + 64 * i];
        f16x4 ov = { (half_t)(v[i].x * inv * wv.x), (half_t)(v[i].y * inv * wv.y),
                     (half_t)(v[i].z * inv * wv.z), (half_t)(v[i].w * inv * wv.w) };
        o4[lane + 64 * i] = ov;
    }
}

// ---------------------------------------------------------------------------
// Cast 7 weight matrices fp32 -> fp16
// ---------------------------------------------------------------------------
struct CastA { const float* s; half_t* d; int n4; };
struct CastArgs { CastA a[7]; };

__global__ void cast_k(CastArgs ca)
{
    CastA a = ca.a[blockIdx.y];
    int i = blockIdx.x * 256 + threadIdx.x;
    if (i >= a.n4) return;
    float4 v = ((const float4*)a.s)[i];
    ((f16x4*)a.d)[i] = (f16x4){ (half_t)v.x, (half_t)v.y, (half_t)v.z, (half_t)v.w };
}

// ---------------------------------------------------------------------------
// RoPE in place on Q,K [b,h,s,64]. Q additionally scaled by 1/sqrt(64).
// ---------------------------------------------------------------------------
__global__ void rope_k(half_t* Q, half_t* Kv)
{
    int idx = blockIdx.x * 256 + threadIdx.x;
    half_t* P = blockIdx.y ? Kv : Q;
    float scq = blockIdx.y ? 1.0f : 0.125f;
    int i = idx & 31;
    int s = (idx >> 5) & 2047;
    int bh = idx >> 16;
    float f = __expf((float)i * -0.28782313662f);
    float ang = (float)s * f;
    float c = cosf(ang), sn = sinf(ang);
    f16x2* p = (f16x2*)(P + ((size_t)bh * 2048 + s) * 64 + 2 * i);
    f16x2 xv = *p;
    float xe = (float)xv[0], xo = (float)xv[1];
    *p = (f16x2){ (half_t)((c * xe - sn * xo) * scq), (half_t)((sn * xe + c * xo) * scq) };
}

// ---------------------------------------------------------------------------
// Causal flash attention, balanced + shuffle-free (see R2 notes).
// Q,K: [b,h,s,64].  VT: [h*64+dk][b*2048+s] (row stride 4096 els).
// ---------------------------------------------------------------------------
__global__ __launch_bounds__(256, 2)
void attn_k(const half_t* __restrict__ Q, const half_t* __restrict__ K,
            const half_t* __restrict__ VT, half_t* __restrict__ O)
{
    __shared__ half_t sK[128 * 64];
    __shared__ half_t sVT[64 * 128];
    __shared__ half_t sP[4][16 * 128];
    const int tid = threadIdx.x, wid = tid >> 6, lane = tid & 63;
    const int lm = lane & 15, lg = lane >> 4;
    const int p = blockIdx.x, bh = blockIdx.y;
    const int b = bh >> 4, hh = bh & 15;
    const size_t base = (size_t)bh * (2048 * 64);

    const int krow = tid >> 3;
    const int kcsw = ((tid & 7) ^ (krow & 7)) << 4;
    const int vrow = tid >> 4;
    const int vcsw = ((tid & 15) ^ (vrow & 15)) << 4;
    const char* gK = (const char*)(K + base);
    const char* gV = (const char*)(VT + (size_t)hh * 64 * 4096 + (size_t)b * 2048);
    char* lK = (char*)sK + tid * 16;
    char* lV = (char*)sVT + tid * 16;
    half_t* sPw = sP[wid];

    f16x8 vone;
#pragma unroll
    for (int j = 0; j < 8; j++) vone[j] = (half_t)1.f;

    for (int ph = 0; ph < 2; ph++) {
        const int qt = ph ? (31 - p) : p;
        const int q0 = qt * 64 + wid * 16;
        const int nT = (qt + 2) >> 1;

        f16x8 bQ[2];
#pragma unroll
        for (int ki = 0; ki < 2; ki++)
            bQ[ki] = *(const f16x8*)(Q + base + (size_t)(q0 + lm) * 64 + ki * 32 + lg * 8);

        fx4 oacc[4] = {};
        fx4 lacc = {};

        for (int t = 0; t < nT; t++) {
            const int kv0 = t * 128;
#pragma unroll
            for (int i = 0; i < 4; i++)
                gld16(gK + (size_t)(kv0 + i * 32 + krow) * 128 + kcsw, lK + i * 4096);
#pragma unroll
            for (int i = 0; i < 4; i++)
                gld16(gV + (size_t)(i * 16 + vrow) * 8192 + (size_t)kv0 * 2 + vcsw, lV + i * 4096);
            __syncthreads();

            fx4 st[8] = {};
#pragma unroll
            for (int ki = 0; ki < 2; ki++) {
#pragma unroll
                for (int mi = 0; mi < 8; mi++) {
                    f16x8 aK = *(const f16x8*)(sK + ((mi * 16 + lm) << 6) +
                                               (((ki * 4 + lg) ^ (lm & 7)) << 3));
                    st[mi] = __builtin_amdgcn_mfma_f32_16x16x32_f16(aK, bQ[ki], st[mi], 0, 0, 0);
                }
            }

            const bool diag = (t == nT - 1);
            const int qg = q0 + lm;
#pragma unroll
            for (int mi = 0; mi < 8; mi++) {
                f16x4 ev;
#pragma unroll
                for (int r = 0; r < 4; r++) {
                    float e = __expf(st[mi][r]);
                    if (diag && (kv0 + mi * 16 + lg * 4 + r > qg)) e = 0.f;
                    ev[r] = (half_t)e;
                }
                *(f16x4*)(sPw + (lm << 7) +
                          ((((mi * 2 + (lg >> 1)) ^ lm) << 3) | ((lg & 1) << 2))) = ev;
            }

#pragma unroll
            for (int k2 = 0; k2 < 4; k2++) {
                f16x8 aP = *(const f16x8*)(sPw + (lm << 7) + (((k2 * 4 + lg) ^ lm) << 3));
#pragma unroll
                for (int ni = 0; ni < 4; ni++) {
                    f16x8 bV = *(const f16x8*)(sVT + ((ni * 16 + lm) << 7) +
                                               (((k2 * 4 + lg) ^ lm) << 3));
                    oacc[ni] = __builtin_amdgcn_mfma_f32_16x16x32_f16(aP, bV, oacc[ni], 0, 0, 0);
                }
                lacc = __builtin_amdgcn_mfma_f32_16x16x32_f16(aP, vone, lacc, 0, 0, 0);
            }
            __syncthreads();
        }

        float inv[4];
#pragma unroll
        for (int r = 0; r < 4; r++) inv[r] = 1.f / lacc[r];
#pragma unroll
        for (int ni = 0; ni < 4; ni++)
#pragma unroll
            for (int r = 0; r < 4; r++) {
                int s = q0 + lg * 4 + r;
                O[((size_t)b * 2048 + s) * 1024 + hh * 64 + ni * 16 + lm] =
                    (half_t)(oacc[ni][r] * inv[r]);
            }
    }
}

// ---------------------------------------------------------------------------
// Workspace layout (half_t units, Mi = 1048576):
//   0..1 wq16 | 1..2 wk16 | 2..3 wv16 | 3..4 wo16   (dead after their GEMM)
//   4..8 w116 | 8..12 w316 | 12..16 w216
//   16..20 h16 (attn O) | 20..24 q16 | 24..28 k16 | 28..32 vt16
//   a16 = 16..32 (fused silu(u)*g; q/k/vt/h dead by then)
//   h216 = 32..36
//   O-proj partials  P0@20, P1@24          (q16,k16 dead after attn)
//   down partials    D0@0, D1@4, D2@8, D3@36  (wq..wo, w1, w3 dead)
// Max extent 40 Mi halfs = 80 MiB.
// ---------------------------------------------------------------------------
extern "C" void kernel_launch(void* const* d_in, const int* in_sizes, int n_in,
                              void* d_out, int out_size, void* d_ws, size_t ws_size,
                              hipStream_t stream)
{
    const float* x   = (const float*)d_in[0];
    const float* wq  = (const float*)d_in[1];
    const float* wk  = (const float*)d_in[2];
    const float* wv  = (const float*)d_in[3];
    const float* wo  = (const float*)d_in[4];
    const float* ln1 = (const float*)d_in[5];
    const float* ln2 = (const float*)d_in[6];
    const float* w1  = (const float*)d_in[7];
    const float* w2  = (const float*)d_in[8];
    const float* w3  = (const float*)d_in[9];

    half_t* W = (half_t*)d_ws;
    const size_t Mi = 1048576;
    half_t* wq16 = W;
    half_t* wk16 = W + Mi;
    half_t* wv16 = W + 2 * Mi;
    half_t* wo16 = W + 3 * Mi;
    half_t* w116 = W + 4 * Mi;
    half_t* w316 = W + 8 * Mi;
    half_t* w216 = W + 12 * Mi;
    half_t* h16  = W + 16 * Mi;
    half_t* q16  = W + 20 * Mi;
    half_t* k16  = W + 24 * Mi;
    half_t* vt16 = W + 28 * Mi;
    half_t* a16  = W + 16 * Mi;
    half_t* h216 = W + 32 * Mi;
    half_t* P0   = W + 20 * Mi;
    half_t* P1   = W + 24 * Mi;
    half_t* D0   = W;
    half_t* D1   = W + 4 * Mi;
    half_t* D2   = W + 8 * Mi;
    half_t* D3   = W + 36 * Mi;

    CastArgs ca;
    ca.a[0] = { wq, wq16, 262144 };
    ca.a[1] = { wk, wk16, 262144 };
    ca.a[2] = { wv, wv16, 262144 };
    ca.a[3] = { wo, wo16, 262144 };
    ca.a[4] = { w1, w116, 1048576 };
    ca.a[5] = { w2, w216, 1048576 };
    ca.a[6] = { w3, w316, 1048576 };

    cast_k<<<dim3(4096, 7), 256, 0, stream>>>(ca);
    rmsnorm_k<<<dim3(1024), 256, 0, stream>>>(x, ln1, h16);
    // Q,K projections (coalesced [b,h,s,dk] epilogue)
    gemm_bt<1><<<dim3(32, 8, 2), 256, 0, stream>>>(h16, wq16, wk16, nullptr,
                                                   q16, k16, nullptr, nullptr,
                                                   4096, 1024, 1024);
    // V^T via swapped-operand GEMM: vt16[dk_g][b*2048+s] = wv·h^T, coalesced
    gemm_bt<4><<<dim3(8, 32, 1), 256, 0, stream>>>(wv16, h16, nullptr, nullptr,
                                                   vt16, nullptr, nullptr, nullptr,
                                                   1024, 4096, 1024);
    rope_k<<<dim3(8192, 2), 256, 0, stream>>>(q16, k16);
    attn_k<<<dim3(16, 32), 256, 0, stream>>>(q16, k16, vt16, h16);
    // O-proj partials (split-K=2)
    gemm_bt<4><<<dim3(32, 8, 2), 256, 0, stream>>>(h16, wo16, nullptr, nullptr,
                                                   P0, P1, nullptr, nullptr,
                                                   4096, 1024, 1024);
    // d_out = x + P0 + P1 ; h216 = rmsnorm(d_out)*ln2   (fused)
    addnorm_k<<<dim3(1024), 256, 0, stream>>>(x, P0, P1, ln2,
                                              (float*)d_out, h216);
    // fused SwiGLU up+gate: a16 = silu(h216·w1^T) * (h216·w3^T)
    gemm_dual<<<dim3(32, 32), 256, 0, stream>>>(h216, w116, w316, a16,
                                                4096, 4096, 1024);
    // down-proj partials (split-K=4), then d_out += sum(D)
    gemm_bt<4><<<dim3(32, 8, 4), 256, 0, stream>>>(a16, w216, nullptr, nullptr,
                                                   D0, D1, D2, D3,
                                                   4096, 1024, 4096);
    reduce4_k<<<dim3(4096), 256, 0, stream>>>(D0, D1, D2, D3, (float*)d_out, 1048576);
    (void)in_sizes; (void)n_in; (void)out_size; (void)ws_size;
}

// Round 8
// 382.325 us; speedup vs baseline: 1.0482x; 1.0482x over previous
//
#include <hip/hip_runtime.h>

typedef _Float16 half_t;
typedef _Float16 f16x8 __attribute__((ext_vector_type(8)));
typedef _Float16 f16x4 __attribute__((ext_vector_type(4)));
typedef _Float16 f16x2 __attribute__((ext_vector_type(2)));
typedef float fx4 __attribute__((ext_vector_type(4)));

typedef __attribute__((address_space(1))) const unsigned int as1_cuint;
typedef __attribute__((address_space(3))) unsigned int as3_uint;

__device__ __forceinline__ void gld16(const void* g, void* l) {
    __builtin_amdgcn_global_load_lds((as1_cuint*)g, (as3_uint*)l, 16, 0, 0);
}

// ---------------------------------------------------------------------------
// GEMM: C[m][n] = sum_k A[m][k] * B[n][k]   (B row-major [N][K], i.e. B^T input)
// 128x128 tile, K-step 32, 4 waves each computing a 64x64 quadrant (4x4 frags).
// Grid: blockIdx.x = M-tile, blockIdx.y = N-tile (XCD swizzle: A-tile sharers
// land on one XCD => A re-reads are L2 hits).
// LDS BANK-CONFLICT SWIZZLE (R8): fragment ds_read_b128 on a 64B-pitch tile is
// 4-way bank conflicted (16 extra cy/read, measured R5-R7). global_load_lds
// pins the LDS destination, so we permute the GLOBAL source chunk instead:
// LDS slot (row, c) holds global chunk c ^ ((row>>1)&3); reads XOR the same key.
// MODE 1: QKV epilogue: z=0,1 -> [b,h,s,dk]; z=2 -> V^T [b,h,dk,s] scatter
// MODE 4: split-K over blockIdx.z; fp16 partial store (no atomics: cross-XCD
//         atomic RMW serialized ~78us in R3/R4).
// ---------------------------------------------------------------------------
template<int MODE>
__global__ __launch_bounds__(256, 2)
void gemm_bt(const half_t* __restrict__ A,
             const half_t* __restrict__ B0, const half_t* __restrict__ B1,
             const half_t* __restrict__ B2,
             half_t* o0, half_t* o1, half_t* o2, half_t* o3,
             int M, int N, int K)
{
    __shared__ half_t sA[128 * 32];
    __shared__ half_t sB[128 * 32];
    const int tid = threadIdx.x;
    const int wid = tid >> 6, lane = tid & 63;
    const int lm = lane & 15, lg = lane >> 4;
    const int wr = wid >> 1, wc = wid & 1;
    const int m0 = blockIdx.x * 128, n0 = blockIdx.y * 128;

    const half_t* Bp = B0;
    half_t* outb = o0;
    if (MODE == 1) {
        if (blockIdx.z == 1) { Bp = B1; outb = o1; }
        else if (blockIdx.z == 2) { Bp = B2; outb = o2; }
    }
    if (MODE == 4) {
        if (blockIdx.z == 1) outb = o1;
        else if (blockIdx.z == 2) outb = o2;
        else if (blockIdx.z == 3) outb = o3;
    }

    int Keff = K, koff = 0;
    if (MODE == 4) { Keff = K / gridDim.z; koff = blockIdx.z * Keff; }

    const int srow = tid >> 2;
    const int scolb = ((tid & 3) ^ ((srow >> 1) & 3)) << 4;   // swizzled source chunk
    const char* gA = (const char*)(A + (size_t)(m0 + srow) * K + koff) + scolb;
    const char* gB = (const char*)(Bp + (size_t)(n0 + srow) * K + koff) + scolb;
    const size_t rstep = (size_t)64 * K * sizeof(half_t);
    char* lA = (char*)sA + tid * 16;
    char* lB = (char*)sB + tid * 16;

    const int ksw = (lm >> 1) & 3;                            // read-side key

    fx4 acc[4][4] = {};

    for (int kt = 0; kt < Keff; kt += 32) {
        gld16(gA, lA);
        gld16(gA + rstep, lA + 4096);
        gld16(gB, lB);
        gld16(gB + rstep, lB + 4096);
        gA += 64; gB += 64;
        __syncthreads();
        f16x8 aF[4], bF[4];
#pragma unroll
        for (int mi = 0; mi < 4; mi++)
            aF[mi] = *(const f16x8*)(sA + (wr * 64 + mi * 16 + lm) * 32 + (lg ^ ksw) * 8);
#pragma unroll
        for (int ni = 0; ni < 4; ni++)
            bF[ni] = *(const f16x8*)(sB + (wc * 64 + ni * 16 + lm) * 32 + (lg ^ ksw) * 8);
#pragma unroll
        for (int mi = 0; mi < 4; mi++)
#pragma unroll
            for (int ni = 0; ni < 4; ni++)
                acc[mi][ni] = __builtin_amdgcn_mfma_f32_16x16x32_f16(aF[mi], bF[ni], acc[mi][ni], 0, 0, 0);
        __syncthreads();
    }

#pragma unroll
    for (int mi = 0; mi < 4; mi++) {
#pragma unroll
        for (int ni = 0; ni < 4; ni++) {
#pragma unroll
            for (int r = 0; r < 4; r++) {
                int m = m0 + wr * 64 + mi * 16 + lg * 4 + r;
                int n = n0 + wc * 64 + ni * 16 + lm;
                float v = acc[mi][ni][r];
                size_t idx = (size_t)m * N + n;
                if (MODE == 1) {
                    int b = m >> 11, s = m & 2047, hh = n >> 6, dk = n & 63;
                    if (blockIdx.z == 2) {
                        outb[((size_t)(b * 16 + hh) * 64 + dk) * 2048 + s] = (half_t)v;
                    } else {
                        outb[((size_t)(b * 16 + hh) * 2048 + s) * 64 + dk] = (half_t)v;
                    }
                } else {
                    outb[idx] = (half_t)v;     // plain / partial, coalesced
                }
            }
        }
    }
}

// ---------------------------------------------------------------------------
// Fused SwiGLU up+gate GEMM: u = A·B1^T, g = A·B2^T (A staged once,
// 32 MFMA per K-step); out = silu(u)*g as fp16. Same swizzle as gemm_bt.
// ---------------------------------------------------------------------------
__global__ __launch_bounds__(256, 2)
void gemm_dual(const half_t* __restrict__ A,
               const half_t* __restrict__ B1, const half_t* __restrict__ B2,
               half_t* __restrict__ out, int M, int N, int K)
{
    __shared__ half_t sA[128 * 32];
    __shared__ half_t sB1[128 * 32];
    __shared__ half_t sB2[128 * 32];
    const int tid = threadIdx.x;
    const int wid = tid >> 6, lane = tid & 63;
    const int lm = lane & 15, lg = lane >> 4;
    const int wr = wid >> 1, wc = wid & 1;
    const int m0 = blockIdx.x * 128, n0 = blockIdx.y * 128;

    const int srow = tid >> 2;
    const int scolb = ((tid & 3) ^ ((srow >> 1) & 3)) << 4;
    const char* gA = (const char*)(A + (size_t)(m0 + srow) * K) + scolb;
    const char* gB1 = (const char*)(B1 + (size_t)(n0 + srow) * K) + scolb;
    const char* gB2 = (const char*)(B2 + (size_t)(n0 + srow) * K) + scolb;
    const size_t rstep = (size_t)64 * K * sizeof(half_t);
    char* lA = (char*)sA + tid * 16;
    char* lB1 = (char*)sB1 + tid * 16;
    char* lB2 = (char*)sB2 + tid * 16;

    const int ksw = (lm >> 1) & 3;

    fx4 accU[4][4] = {};
    fx4 accG[4][4] = {};

    for (int kt = 0; kt < K; kt += 32) {
        gld16(gA, lA);
        gld16(gA + rstep, lA + 4096);
        gld16(gB1, lB1);
        gld16(gB1 + rstep, lB1 + 4096);
        gld16(gB2, lB2);
        gld16(gB2 + rstep, lB2 + 4096);
        gA += 64; gB1 += 64; gB2 += 64;
        __syncthreads();
        f16x8 aF[4], b1F[4], b2F[4];
#pragma unroll
        for (int mi = 0; mi < 4; mi++)
            aF[mi] = *(const f16x8*)(sA + (wr * 64 + mi * 16 + lm) * 32 + (lg ^ ksw) * 8);
#pragma unroll
        for (int ni = 0; ni < 4; ni++) {
            b1F[ni] = *(const f16x8*)(sB1 + (wc * 64 + ni * 16 + lm) * 32 + (lg ^ ksw) * 8);
            b2F[ni] = *(const f16x8*)(sB2 + (wc * 64 + ni * 16 + lm) * 32 + (lg ^ ksw) * 8);
        }
#pragma unroll
        for (int mi = 0; mi < 4; mi++)
#pragma unroll
            for (int ni = 0; ni < 4; ni++) {
                accU[mi][ni] = __builtin_amdgcn_mfma_f32_16x16x32_f16(aF[mi], b1F[ni], accU[mi][ni], 0, 0, 0);
                accG[mi][ni] = __builtin_amdgcn_mfma_f32_16x16x32_f16(aF[mi], b2F[ni], accG[mi][ni], 0, 0, 0);
            }
        __syncthreads();
    }

#pragma unroll
    for (int mi = 0; mi < 4; mi++) {
#pragma unroll
        for (int ni = 0; ni < 4; ni++) {
#pragma unroll
            for (int r = 0; r < 4; r++) {
                int m = m0 + wr * 64 + mi * 16 + lg * 4 + r;
                int n = n0 + wc * 64 + ni * 16 + lm;
                float u = accU[mi][ni][r];
                float g = accG[mi][ni][r];
                out[(size_t)m * N + n] = (half_t)(u / (1.f + __expf(-u)) * g);
            }
        }
    }
}

// ---------------------------------------------------------------------------
// Fused O-proj combine + residual + RMSNorm:
//   t = x + p0 + p1;  outF = t;  outH = rmsnorm(t)*w  (fp16)
// ---------------------------------------------------------------------------
__global__ __launch_bounds__(256, 4)
void addnorm_k(const float* __restrict__ x,
               const half_t* __restrict__ p0, const half_t* __restrict__ p1,
               const float* __restrict__ w,
               float* __restrict__ outF, half_t* __restrict__ outH)
{
    int row = blockIdx.x * 4 + (threadIdx.x >> 6);
    int lane = threadIdx.x & 63;
    const float4* xr = (const float4*)(x + (size_t)row * 1024);
    const f16x4* p0r = (const f16x4*)(p0 + (size_t)row * 1024);
    const f16x4* p1r = (const f16x4*)(p1 + (size_t)row * 1024);
    float4 v[4];
    float s = 0.f;
#pragma unroll
    for (int i = 0; i < 4; i++) {
        float4 xv = xr[lane + 64 * i];
        f16x4 a0 = p0r[lane + 64 * i];
        f16x4 a1 = p1r[lane + 64 * i];
        v[i].x = xv.x + (float)a0[0] + (float)a1[0];
        v[i].y = xv.y + (float)a0[1] + (float)a1[1];
        v[i].z = xv.z + (float)a0[2] + (float)a1[2];
        v[i].w = xv.w + (float)a0[3] + (float)a1[3];
        s += v[i].x * v[i].x + v[i].y * v[i].y + v[i].z * v[i].z + v[i].w * v[i].w;
    }
#pragma unroll
    for (int o = 32; o > 0; o >>= 1) s += __shfl_xor(s, o);
    float inv = rsqrtf(s * (1.f / 1024.f) + 1e-5f);
    const float4* w4 = (const float4*)w;
    float4* oF = (float4*)(outF + (size_t)row * 1024);
    f16x4* oH = (f16x4*)(outH + (size_t)row * 1024);
#pragma unroll
    for (int i = 0; i < 4; i++) {
        oF[lane + 64 * i] = v[i];
        float4 wv = w4[lane + 64 * i];
        f16x4 ov = { (half_t)(v[i].x * inv * wv.x), (half_t)(v[i].y * inv * wv.y),
                     (half_t)(v[i].z * inv * wv.z), (half_t)(v[i].w * inv * wv.w) };
        oH[lane + 64 * i] = ov;
    }
}

// ---------------------------------------------------------------------------
// Split-K=4 combine: out = out + p0 + p1 + p2 + p3
// ---------------------------------------------------------------------------
__global__ __launch_bounds__(256, 8)
void reduce4_k(const half_t* __restrict__ p0, const half_t* __restrict__ p1,
               const half_t* __restrict__ p2, const half_t* __restrict__ p3,
               float* __restrict__ out, int n4)
{
    int i = blockIdx.x * 256 + threadIdx.x;
    if (i >= n4) return;
    float4 b = ((const float4*)out)[i];
    f16x4 a0 = ((const f16x4*)p0)[i];
    f16x4 a1 = ((const f16x4*)p1)[i];
    f16x4 a2 = ((const f16x4*)p2)[i];
    f16x4 a3 = ((const f16x4*)p3)[i];
    float4 o = { b.x + (float)a0[0] + (float)a1[0] + (float)a2[0] + (float)a3[0],
                 b.y + (float)a0[1] + (float)a1[1] + (float)a2[1] + (float)a3[1],
                 b.z + (float)a0[2] + (float)a1[2] + (float)a2[2] + (float)a3[2],
                 b.w + (float)a0[3] + (float)a1[3] + (float)a2[3] + (float)a3[3] };
    ((float4*)out)[i] = o;
}

// ---------------------------------------------------------------------------
// RMSNorm: one wave per row of 1024 fp32, output fp16
// ---------------------------------------------------------------------------
__global__ __launch_bounds__(256, 4)
void rmsnorm_k(const float* __restrict__ x, const float* __restrict__ w,
               half_t* __restrict__ out)
{
    int row = blockIdx.x * 4 + (threadIdx.x >> 6);
    int lane = threadIdx.x & 63;
    const float4* xr = (const float4*)(x + (size_t)row * 1024);
    float4 v[4];
    float s = 0.f;
#pragma unroll
    for (int i = 0; i < 4; i++) {
        v[i] = xr[lane + 64 * i];
        s += v[i].x * v[i].x + v[i].y * v[i].y + v[i].z * v[i].z + v[i].w * v[i].w;
    }
#pragma unroll
    for (int o = 32; o > 0; o >>= 1) s += __shfl_xor(s, o);
    float inv = rsqrtf(s * (1.f / 1024.f) + 1e-5f);
    const float4* w4 = (const float4*)w;
    f16x4* o4 = (f16x4*)(out + (size_t)row * 1024);
#pragma unroll
    for (int i = 0; i < 4; i++) {
        float4 wv = w4[lane + 64 * i];
        f16x4 ov = { (half_t)(v[i].x * inv * wv.x), (half_t)(v[i].y * inv * wv.y),
                     (half_t)(v[i].z * inv * wv.z), (half_t)(v[i].w * inv * wv.w) };
        o4[lane + 64 * i] = ov;
    }
}

// ---------------------------------------------------------------------------
// Cast 7 weight matrices fp32 -> fp16
// ---------------------------------------------------------------------------
struct CastA { const float* s; half_t* d; int n4; };
struct CastArgs { CastA a[7]; };

__global__ void cast_k(CastArgs ca)
{
    CastA a = ca.a[blockIdx.y];
    int i = blockIdx.x * 256 + threadIdx.x;
    if (i >= a.n4) return;
    float4 v = ((const float4*)a.s)[i];
    ((f16x4*)a.d)[i] = (f16x4){ (half_t)v.x, (half_t)v.y, (half_t)v.z, (half_t)v.w };
}

// ---------------------------------------------------------------------------
// RoPE in place on Q,K [b,h,s,64]. Q additionally scaled by 1/sqrt(64).
// ---------------------------------------------------------------------------
__global__ void rope_k(half_t* Q, half_t* Kv)
{
    int idx = blockIdx.x * 256 + threadIdx.x;
    half_t* P = blockIdx.y ? Kv : Q;
    float scq = blockIdx.y ? 1.0f : 0.125f;
    int i = idx & 31;
    int s = (idx >> 5) & 2047;
    int bh = idx >> 16;
    float f = __expf((float)i * -0.28782313662f);
    float ang = (float)s * f;
    float c = cosf(ang), sn = sinf(ang);
    f16x2* p = (f16x2*)(P + ((size_t)bh * 2048 + s) * 64 + 2 * i);
    f16x2 xv = *p;
    float xe = (float)xv[0], xo = (float)xv[1];
    *p = (f16x2){ (half_t)((c * xe - sn * xo) * scq), (half_t)((sn * xe + c * xo) * scq) };
}

// ---------------------------------------------------------------------------
// Causal flash attention, balanced + shuffle-free (see R2 notes).
// Q,K: [b,h,s,64].  VT: [b,h,dk,s] (row stride 2048 els).
// ---------------------------------------------------------------------------
__global__ __launch_bounds__(256, 2)
void attn_k(const half_t* __restrict__ Q, const half_t* __restrict__ K,
            const half_t* __restrict__ VT, half_t* __restrict__ O)
{
    __shared__ half_t sK[128 * 64];
    __shared__ half_t sVT[64 * 128];
    __shared__ half_t sP[4][16 * 128];
    const int tid = threadIdx.x, wid = tid >> 6, lane = tid & 63;
    const int lm = lane & 15, lg = lane >> 4;
    const int p = blockIdx.x, bh = blockIdx.y;
    const int b = bh >> 4, hh = bh & 15;
    const size_t base = (size_t)bh * (2048 * 64);

    const int krow = tid >> 3;
    const int kcsw = ((tid & 7) ^ (krow & 7)) << 4;
    const int vrow = tid >> 4;
    const int vcsw = ((tid & 15) ^ (vrow & 15)) << 4;
    const char* gK = (const char*)(K + base);
    const char* gV = (const char*)(VT + base);
    char* lK = (char*)sK + tid * 16;
    char* lV = (char*)sVT + tid * 16;
    half_t* sPw = sP[wid];

    f16x8 vone;
#pragma unroll
    for (int j = 0; j < 8; j++) vone[j] = (half_t)1.f;

    for (int ph = 0; ph < 2; ph++) {
        const int qt = ph ? (31 - p) : p;
        const int q0 = qt * 64 + wid * 16;
        const int nT = (qt + 2) >> 1;

        f16x8 bQ[2];
#pragma unroll
        for (int ki = 0; ki < 2; ki++)
            bQ[ki] = *(const f16x8*)(Q + base + (size_t)(q0 + lm) * 64 + ki * 32 + lg * 8);

        fx4 oacc[4] = {};
        fx4 lacc = {};

        for (int t = 0; t < nT; t++) {
            const int kv0 = t * 128;
#pragma unroll
            for (int i = 0; i < 4; i++)
                gld16(gK + (size_t)(kv0 + i * 32 + krow) * 128 + kcsw, lK + i * 4096);
#pragma unroll
            for (int i = 0; i < 4; i++)
                gld16(gV + (size_t)(i * 16 + vrow) * 4096 + (size_t)kv0 * 2 + vcsw, lV + i * 4096);
            __syncthreads();

            fx4 st[8] = {};
#pragma unroll
            for (int ki = 0; ki < 2; ki++) {
#pragma unroll
                for (int mi = 0; mi < 8; mi++) {
                    f16x8 aK = *(const f16x8*)(sK + ((mi * 16 + lm) << 6) +
                                               (((ki * 4 + lg) ^ (lm & 7)) << 3));
                    st[mi] = __builtin_amdgcn_mfma_f32_16x16x32_f16(aK, bQ[ki], st[mi], 0, 0, 0);
                }
            }

            const bool diag = (t == nT - 1);
            const int qg = q0 + lm;
#pragma unroll
            for (int mi = 0; mi < 8; mi++) {
                f16x4 ev;
#pragma unroll
                for (int r = 0; r < 4; r++) {
                    float e = __expf(st[mi][r]);
                    if (diag && (kv0 + mi * 16 + lg * 4 + r > qg)) e = 0.f;
                    ev[r] = (half_t)e;
                }
                *(f16x4*)(sPw + (lm << 7) +
                          ((((mi * 2 + (lg >> 1)) ^ lm) << 3) | ((lg & 1) << 2))) = ev;
            }

#pragma unroll
            for (int k2 = 0; k2 < 4; k2++) {
                f16x8 aP = *(const f16x8*)(sPw + (lm << 7) + (((k2 * 4 + lg) ^ lm) << 3));
#pragma unroll
                for (int ni = 0; ni < 4; ni++) {
                    f16x8 bV = *(const f16x8*)(sVT + ((ni * 16 + lm) << 7) +
                                               (((k2 * 4 + lg) ^ lm) << 3));
                    oacc[ni] = __builtin_amdgcn_mfma_f32_16x16x32_f16(aP, bV, oacc[ni], 0, 0, 0);
                }
                lacc = __builtin_amdgcn_mfma_f32_16x16x32_f16(aP, vone, lacc, 0, 0, 0);
            }
            __syncthreads();
        }

        float inv[4];
#pragma unroll
        for (int r = 0; r < 4; r++) inv[r] = 1.f / lacc[r];
#pragma unroll
        for (int ni = 0; ni < 4; ni++)
#pragma unroll
            for (int r = 0; r < 4; r++) {
                int s = q0 + lg * 4 + r;
                O[((size_t)b * 2048 + s) * 1024 + hh * 64 + ni * 16 + lm] =
                    (half_t)(oacc[ni][r] * inv[r]);
            }
    }
}

// ---------------------------------------------------------------------------
// Workspace layout (half_t units, Mi = 1048576):
//   0..1 wq16 | 1..2 wk16 | 2..3 wv16 | 3..4 wo16   (dead after their GEMM)
//   4..8 w116 | 8..12 w316 | 12..16 w216
//   16..20 h16 (attn O) | 20..24 q16 | 24..28 k16 | 28..32 vt16
//   a16 = 16..32 (fused silu(u)*g; q/k/vt/h dead by then)
//   h216 = 32..36
//   O-proj partials  P0@20, P1@24          (q16,k16 dead after attn)
//   down partials    D0@0, D1@4, D2@8, D3@36  (wq..wo, w1, w3 dead)
// Max extent 40 Mi halfs = 80 MiB.
// ---------------------------------------------------------------------------
extern "C" void kernel_launch(void* const* d_in, const int* in_sizes, int n_in,
                              void* d_out, int out_size, void* d_ws, size_t ws_size,
                              hipStream_t stream)
{
    const float* x   = (const float*)d_in[0];
    const float* wq  = (const float*)d_in[1];
    const float* wk  = (const float*)d_in[2];
    const float* wv  = (const float*)d_in[3];
    const float* wo  = (const float*)d_in[4];
    const float* ln1 = (const float*)d_in[5];
    const float* ln2 = (const float*)d_in[6];
    const float* w1  = (const float*)d_in[7];
    const float* w2  = (const float*)d_in[8];
    const float* w3  = (const float*)d_in[9];

    half_t* W = (half_t*)d_ws;
    const size_t Mi = 1048576;
    half_t* wq16 = W;
    half_t* wk16 = W + Mi;
    half_t* wv16 = W + 2 * Mi;
    half_t* wo16 = W + 3 * Mi;
    half_t* w116 = W + 4 * Mi;
    half_t* w316 = W + 8 * Mi;
    half_t* w216 = W + 12 * Mi;
    half_t* h16  = W + 16 * Mi;
    half_t* q16  = W + 20 * Mi;
    half_t* k16  = W + 24 * Mi;
    half_t* vt16 = W + 28 * Mi;
    half_t* a16  = W + 16 * Mi;
    half_t* h216 = W + 32 * Mi;
    half_t* P0   = W + 20 * Mi;
    half_t* P1   = W + 24 * Mi;
    half_t* D0   = W;
    half_t* D1   = W + 4 * Mi;
    half_t* D2   = W + 8 * Mi;
    half_t* D3   = W + 36 * Mi;

    CastArgs ca;
    ca.a[0] = { wq, wq16, 262144 };
    ca.a[1] = { wk, wk16, 262144 };
    ca.a[2] = { wv, wv16, 262144 };
    ca.a[3] = { wo, wo16, 262144 };
    ca.a[4] = { w1, w116, 1048576 };
    ca.a[5] = { w2, w216, 1048576 };
    ca.a[6] = { w3, w316, 1048576 };

    cast_k<<<dim3(4096, 7), 256, 0, stream>>>(ca);
    rmsnorm_k<<<dim3(1024), 256, 0, stream>>>(x, ln1, h16);
    gemm_bt<1><<<dim3(32, 8, 3), 256, 0, stream>>>(h16, wq16, wk16, wv16,
                                                   q16, k16, vt16, nullptr,
                                                   4096, 1024, 1024);
    rope_k<<<dim3(8192, 2), 256, 0, stream>>>(q16, k16);
    attn_k<<<dim3(16, 32), 256, 0, stream>>>(q16, k16, vt16, h16);
    // O-proj partials (split-K=2)
    gemm_bt<4><<<dim3(32, 8, 2), 256, 0, stream>>>(h16, wo16, nullptr, nullptr,
                                                   P0, P1, nullptr, nullptr,
                                                   4096, 1024, 1024);
    // d_out = x + P0 + P1 ; h216 = rmsnorm(d_out)*ln2   (fused)
    addnorm_k<<<dim3(1024), 256, 0, stream>>>(x, P0, P1, ln2,
                                              (float*)d_out, h216);
    // fused SwiGLU up+gate: a16 = silu(h216·w1^T) * (h216·w3^T)
    gemm_dual<<<dim3(32, 32), 256, 0, stream>>>(h216, w116, w316, a16,
                                                4096, 4096, 1024);
    // down-proj partials (split-K=4), then d_out += sum(D)
    gemm_bt<4><<<dim3(32, 8, 4), 256, 0, stream>>>(a16, w216, nullptr, nullptr,
                                                   D0, D1, D2, D3,
                                                   4096, 1024, 4096);
    reduce4_k<<<dim3(4096), 256, 0, stream>>>(D0, D1, D2, D3, (float*)d_out, 1048576);
    (void)in_sizes; (void)n_in; (void)out_size; (void)ws_size;
}